// Round 1
// baseline (802.693 us; speedup 1.0000x reference)
//
#include <hip/hip_runtime.h>
#include <hip/hip_bf16.h>
#include <cstdint>
#include <math.h>

#define B_ 32
#define T_ 336
#define N_ 321
#define L_ 2
#define E_ 4
#define F_ 2048
#define P_ 96
#define TPAD 352   // T padded to multiple of 32 (K of GEMM1)
#define NPAD 384   // N padded to multiple of 128 (M tiles)
#define TTPAD 384  // T padded to multiple of 128 (N tiles of GEMM2)

typedef __hip_bfloat16 bf16;
typedef __attribute__((ext_vector_type(8))) __bf16 bf16x8;
typedef __attribute__((ext_vector_type(4))) float f32x4;

__device__ __forceinline__ void async_copy16(const void* g, void* l) {
  __builtin_amdgcn_global_load_lds(
      (__attribute__((address_space(1))) void*)(uintptr_t)g,
      (__attribute__((address_space(3))) void*)(unsigned int)(uintptr_t)l,
      16, 0, 0);
}

__device__ __forceinline__ float bflo(unsigned u) { return __uint_as_float(u << 16); }
__device__ __forceinline__ float bfhi(unsigned u) { return __uint_as_float(u & 0xffff0000u); }

// ---------------- transpose + cast fp32 -> bf16 (K-contiguous operand prep) ----------
// src slice: R x C row-major fp32. dst slice: Cp x Rp row-major bf16, dst[c][r]=src[r][c],
// zero where r>=R or c>=C.
__global__ void transpose_cast_kernel(const float* __restrict__ src, bf16* __restrict__ dst,
                                      int R, int C, int Rp, int Cp,
                                      long long sStride, long long dStride) {
  __shared__ float tile[32][33];
  const float* s = src + (size_t)blockIdx.z * sStride;
  bf16* d = dst + (size_t)blockIdx.z * dStride;
  int r0 = blockIdx.x * 32, c0 = blockIdx.y * 32;
  int tx = threadIdx.x, ty = threadIdx.y;
  #pragma unroll
  for (int ii = 0; ii < 4; ii++) {
    int rl = ty * 4 + ii;
    int r = r0 + rl, c = c0 + tx;
    tile[rl][tx] = (r < R && c < C) ? s[(size_t)r * C + c] : 0.f;
  }
  __syncthreads();
  #pragma unroll
  for (int ii = 0; ii < 4; ii++) {
    int cl = ty * 4 + ii;
    int cd = c0 + cl, rd = r0 + tx;
    if (cd < Cp && rd < Rp)
      d[(size_t)cd * Rp + rd] = __float2bfloat16(tile[tx][cl]);
  }
}

// ---------------- RevIN over time axis: out[b,t,n] = (x[b,t,n,0]-mu)/sd -------------
__global__ void revin_kernel(const float* __restrict__ x, float* __restrict__ out) {
  int b = blockIdx.x;
  int n = blockIdx.y * 192 + threadIdx.x;
  if (n >= N_) return;
  const float* xp = x + ((size_t)b * T_ * N_ + n) * 3;
  float s1 = 0.f, s2 = 0.f;
  for (int t = 0; t < T_; t++) {
    float v = xp[(size_t)t * N_ * 3];
    s1 += v; s2 += v * v;
  }
  float mu = s1 / T_;
  float var = s2 / T_ - mu * mu;
  float inv = 1.f / sqrtf(var + 1e-5f);
  for (int t = 0; t < T_; t++) {
    float v = (xp[(size_t)t * N_ * 3] - mu) * inv;
    out[((size_t)b * T_ + t) * N_ + n] = v;
  }
}

// ---------------- pack: out (+ optional per-expert be2 bias) -> Abuf bf16 (B,NPAD,TPAD)
__global__ void pack_kernel(float* __restrict__ out, bf16* __restrict__ Abuf,
                            const float* __restrict__ be2,
                            const int* __restrict__ pair_e, const float* __restrict__ pair_gate,
                            int layer) {
  __shared__ float tile[32][33];
  int b = blockIdx.z;
  int t0 = blockIdx.x * 32, n0 = blockIdx.y * 32;
  int tx = threadIdx.x, ty = threadIdx.y;
  bool dob = layer >= 0;
  float g0 = 0.f, g1 = 0.f; int e0 = 0, e1 = 0;
  if (dob) {
    e0 = pair_e[b * 2]; e1 = pair_e[b * 2 + 1];
    g0 = pair_gate[b * 2]; g1 = pair_gate[b * 2 + 1];
  }
  #pragma unroll
  for (int ii = 0; ii < 4; ii++) {
    int i = ty * 4 + ii;
    int t = t0 + i, n = n0 + tx;
    float v = 0.f;
    if (t < T_ && n < N_) {
      v = out[((size_t)b * T_ + t) * N_ + n];
      if (dob) {
        v += g0 * be2[(layer * E_ + e0) * T_ + t] + g1 * be2[(layer * E_ + e1) * T_ + t];
        out[((size_t)b * T_ + t) * N_ + n] = v;
      }
    }
    tile[i][tx] = v;
  }
  __syncthreads();
  #pragma unroll
  for (int ii = 0; ii < 4; ii++) {
    int i = ty * 4 + ii;           // n-local
    int n = n0 + i, t = t0 + tx;
    if (n < NPAD && t < TPAD)
      Abuf[((size_t)b * NPAD + n) * TPAD + t] = __float2bfloat16(tile[tx][i]);
  }
}

// ---------------- gating: logits[b,e] = (mean_n out[b,t,n]) @ Wg[l] -----------------
__global__ void gate1_kernel(const float* __restrict__ out, const float* __restrict__ Wg,
                             float* __restrict__ logits, int layer) {
  __shared__ float red[4][512];
  int b = blockIdx.x, tid = threadIdx.x; // 384 threads
  float cm = 0.f;
  if (tid < T_) {
    const float* p = out + ((size_t)b * T_ + tid) * N_;
    float s = 0.f;
    for (int n = 0; n < N_; n++) s += p[n];
    cm = s / (float)N_;
  }
  #pragma unroll
  for (int e = 0; e < 4; e++)
    red[e][tid] = (tid < T_) ? cm * Wg[(layer * T_ + tid) * E_ + e] : 0.f;
  if (tid < 128) {
    #pragma unroll
    for (int e = 0; e < 4; e++) red[e][384 + tid] = 0.f;
  }
  __syncthreads();
  for (int s = 256; s > 0; s >>= 1) {
    if (tid < s) {
      #pragma unroll
      for (int e = 0; e < 4; e++) red[e][tid] += red[e][tid + s];
    }
    __syncthreads();
  }
  if (tid < 4) logits[b * 4 + tid] = red[tid][0];
}

// top-2 + softmax + importance + cv^2 loss
__global__ void gate2_kernel(const float* __restrict__ logits, int* __restrict__ pair_e,
                             float* __restrict__ pair_gate, float* __restrict__ loss_partial,
                             int layer) {
  __shared__ float gates[32][4];
  __shared__ float imp[4];
  int tid = threadIdx.x;
  if (tid < 32) {
    float v[4];
    #pragma unroll
    for (int e = 0; e < 4; e++) v[e] = logits[tid * 4 + e];
    int i0 = 0;
    for (int e = 1; e < 4; e++) if (v[e] > v[i0]) i0 = e;     // lowest index wins ties
    int i1 = -1;
    for (int e = 0; e < 4; e++) {
      if (e == i0) continue;
      if (i1 < 0 || v[e] > v[i1]) i1 = e;
    }
    float ex = expf(v[i1] - v[i0]);
    float g0 = 1.f / (1.f + ex);
    float g1 = ex / (1.f + ex);
    pair_e[tid * 2] = i0; pair_e[tid * 2 + 1] = i1;
    pair_gate[tid * 2] = g0; pair_gate[tid * 2 + 1] = g1;
    #pragma unroll
    for (int e = 0; e < 4; e++) gates[tid][e] = 0.f;
    gates[tid][i0] = g0; gates[tid][i1] = g1;
  }
  __syncthreads();
  if (tid < 4) {
    float s = 0.f;
    for (int bb = 0; bb < 32; bb++) s += gates[bb][tid];
    imp[tid] = s;
  }
  __syncthreads();
  if (tid == 0) {
    float m = (imp[0] + imp[1] + imp[2] + imp[3]) * 0.25f;
    float va = 0.f;
    #pragma unroll
    for (int e = 0; e < 4; e++) { float d = imp[e] - m; va += d * d; }
    va *= 0.25f;
    loss_partial[layer] = 0.01f * (va / (m * m + 1e-10f));
  }
}

// ---------------- GEMM1: h[pair] = gate * relu(Abuf[b] @ We1[l,e] + be1) ------------
// A: (NPAD,TPAD) bf16 K-contig.  B: W1T (F,TPAD) bf16 K-contig.  C tile 128x128.
__global__ __launch_bounds__(256) void gemm1_kernel(
    const bf16* __restrict__ Abuf, const bf16* __restrict__ W1T,
    const float* __restrict__ be1, const int* __restrict__ pair_e,
    const float* __restrict__ pair_gate, bf16* __restrict__ h, int layer) {
  __shared__ __align__(16) bf16 As[128 * 32];
  __shared__ __align__(16) bf16 Bs[128 * 32];
  __shared__ float bias_s[128];

  const int tid = threadIdx.x;
  const int w = tid >> 6, lane = tid & 63;
  const int pair = blockIdx.z;
  const int b = pair >> 1;
  const int e = pair_e[pair];
  const float gate = pair_gate[pair];
  const int m0 = blockIdx.y * 128;  // n-dim
  const int f0 = blockIdx.x * 128;

  const bf16* Ag = Abuf + (size_t)b * NPAD * TPAD + (size_t)m0 * TPAD;
  const bf16* Bg = W1T + ((size_t)(layer * E_ + e) * F_ + f0) * TPAD;
  if (tid < 128) bias_s[tid] = be1[(size_t)(layer * E_ + e) * F_ + f0 + tid];

  f32x4 acc[4][4];
  const f32x4 zero = {0.f, 0.f, 0.f, 0.f};
  #pragma unroll
  for (int i = 0; i < 4; i++)
    #pragma unroll
    for (int j = 0; j < 4; j++) acc[i][j] = zero;

  const int wm = w >> 1, wn = w & 1;
  const int lrow = lane >> 2;
  const int lkoff = (lane & 3) * 8;
  const int quad = lane >> 4;
  const int l15 = lane & 15;

  for (int kk = 0; kk < TPAD / 32; ++kk) {
    const int k0 = kk * 32;
    #pragma unroll
    for (int i = 0; i < 2; i++) {
      int r = (w * 2 + i) * 16 + lrow;
      async_copy16(Ag + (size_t)r * TPAD + k0 + lkoff, As + (w * 2 + i) * 512);
    }
    #pragma unroll
    for (int i = 0; i < 2; i++) {
      int r = (w * 2 + i) * 16 + lrow;
      async_copy16(Bg + (size_t)r * TPAD + k0 + lkoff, Bs + (w * 2 + i) * 512);
    }
    __syncthreads();
    bf16x8 af[4], bfr[4];
    #pragma unroll
    for (int mi = 0; mi < 4; mi++)
      af[mi] = *(const bf16x8*)(As + (wm * 64 + mi * 16 + l15) * 32 + quad * 8);
    #pragma unroll
    for (int ni = 0; ni < 4; ni++)
      bfr[ni] = *(const bf16x8*)(Bs + (wn * 64 + ni * 16 + l15) * 32 + quad * 8);
    #pragma unroll
    for (int mi = 0; mi < 4; mi++)
      #pragma unroll
      for (int ni = 0; ni < 4; ni++)
        acc[mi][ni] = __builtin_amdgcn_mfma_f32_16x16x32_bf16(af[mi], bfr[ni], acc[mi][ni], 0, 0, 0);
    __syncthreads();
  }

  // epilogue: bias + relu + gate, LDS transpose for coalesced bf16 stores
  bf16* tw0 = As + w * 1024;
  bf16* tw1 = Bs + w * 1024;
  size_t hbase = (size_t)pair * NPAD * F_ + f0 + wn * 64;
  #pragma unroll
  for (int mi = 0; mi < 4; mi++) {
    bf16* tw = (mi & 1) ? tw1 : tw0;
    #pragma unroll
    for (int ni = 0; ni < 4; ni++) {
      float bias = bias_s[wn * 64 + ni * 16 + l15];
      #pragma unroll
      for (int r = 0; r < 4; r++) {
        float v = acc[mi][ni][r] + bias;
        v = fmaxf(v, 0.f) * gate;
        tw[(quad * 4 + r) * 64 + ni * 16 + l15] = __float2bfloat16(v);
      }
    }
    int row = lane >> 2;            // 0..15
    int fpart = (lane & 3) * 16;    // 0,16,32,48
    int ng = m0 + wm * 64 + mi * 16 + row;
    const uint4* sp = (const uint4*)(tw + row * 64 + fpart);
    uint4 d0 = sp[0];
    uint4 d1 = sp[1];
    uint4* dp = (uint4*)(h + hbase + (size_t)ng * F_ + fpart);
    dp[0] = d0; dp[1] = d1;
  }
}

// ---------------- GEMM2: out[b,t,n] += sum_j h[b*2+j] @ We2[l,e_j]  (K=4096) --------
// A: h (NPAD,F) bf16.  B: W2T (TTPAD,F) bf16 K-contig.  Tile 64(n) x 128(t).
__global__ __launch_bounds__(256) void gemm2_kernel(
    const bf16* __restrict__ h, const bf16* __restrict__ W2T,
    const int* __restrict__ pair_e, float* __restrict__ out, int layer) {
  __shared__ __align__(16) bf16 As2[64 * 32];
  __shared__ __align__(16) bf16 Bs2[128 * 32];
  const int tid = threadIdx.x;
  const int w = tid >> 6, lane = tid & 63;
  const int b = blockIdx.z;
  const int n0 = blockIdx.y * 64;
  const int t0 = blockIdx.x * 128;
  const int e0 = pair_e[b * 2], e1 = pair_e[b * 2 + 1];
  const bf16* A0 = h + (size_t)(b * 2) * NPAD * F_ + (size_t)n0 * F_;
  const bf16* A1 = h + (size_t)(b * 2 + 1) * NPAD * F_ + (size_t)n0 * F_;
  const bf16* B0 = W2T + ((size_t)(layer * E_ + e0) * TTPAD + t0) * F_;
  const bf16* B1 = W2T + ((size_t)(layer * E_ + e1) * TTPAD + t0) * F_;
  const int lrow = lane >> 2, lkoff = (lane & 3) * 8, quad = lane >> 4, l15 = lane & 15;
  const int wm = w >> 1, wn = w & 1;

  f32x4 acc[2][4];
  const f32x4 zero = {0.f, 0.f, 0.f, 0.f};
  #pragma unroll
  for (int i = 0; i < 2; i++)
    #pragma unroll
    for (int j = 0; j < 4; j++) acc[i][j] = zero;

  for (int kk = 0; kk < 128; ++kk) {
    const bf16* Ab = (kk < 64) ? A0 : A1;
    const bf16* Bb = (kk < 64) ? B0 : B1;
    const int fl = (kk & 63) * 32;
    async_copy16(Ab + (size_t)(w * 16 + lrow) * F_ + fl + lkoff, As2 + w * 512);
    #pragma unroll
    for (int i = 0; i < 2; i++) {
      int r = (w * 2 + i) * 16 + lrow;
      async_copy16(Bb + (size_t)r * F_ + fl + lkoff, Bs2 + (w * 2 + i) * 512);
    }
    __syncthreads();
    bf16x8 af[2], bfr[4];
    #pragma unroll
    for (int mi = 0; mi < 2; mi++)
      af[mi] = *(const bf16x8*)(As2 + (wm * 32 + mi * 16 + l15) * 32 + quad * 8);
    #pragma unroll
    for (int ni = 0; ni < 4; ni++)
      bfr[ni] = *(const bf16x8*)(Bs2 + (wn * 64 + ni * 16 + l15) * 32 + quad * 8);
    #pragma unroll
    for (int mi = 0; mi < 2; mi++)
      #pragma unroll
      for (int ni = 0; ni < 4; ni++)
        acc[mi][ni] = __builtin_amdgcn_mfma_f32_16x16x32_bf16(af[mi], bfr[ni], acc[mi][ni], 0, 0, 0);
    __syncthreads();
  }

  // epilogue: residual RMW into out (each (n,t) owned by exactly one block)
  #pragma unroll
  for (int mi = 0; mi < 2; mi++) {
    #pragma unroll
    for (int ni = 0; ni < 4; ni++) {
      int n = n0 + wm * 32 + mi * 16 + quad * 4;
      int t = t0 + wn * 64 + ni * 16 + l15;
      if (t < T_) {
        float* po = out + ((size_t)b * T_ + t) * N_ + n;
        #pragma unroll
        for (int r = 0; r < 4; r++)
          if (n + r < N_) po[r] += acc[mi][ni][r];
      }
    }
  }
}

// ---------------- projection head -------------------------------------------------
__global__ __launch_bounds__(256) void proj_kernel(
    const bf16* __restrict__ Abuf, const bf16* __restrict__ P1T, const float* __restrict__ P1b,
    const bf16* __restrict__ P2T, const float* __restrict__ P2b,
    const float* __restrict__ loss_partial, float* __restrict__ dout) {
  __shared__ __align__(16) bf16 Ash[32 * T_];
  __shared__ float hp[32 * 96];
  const int tid = threadIdx.x;
  const int b = blockIdx.y, n0 = blockIdx.x * 32;

  for (int idx = tid; idx < 32 * 42; idx += 256) {
    int row = idx / 42, c8 = idx % 42;
    *(uint4*)(Ash + row * T_ + c8 * 8) =
        *(const uint4*)(Abuf + ((size_t)b * NPAD + n0 + row) * TPAD + c8 * 8);
  }
  __syncthreads();

  #pragma unroll
  for (int it = 0; it < 12; ++it) {
    int idx = tid + it * 256;        // < 3072 = 32*96
    int nl = idx / 96, p = idx % 96;
    const unsigned* ap = (const unsigned*)(Ash + nl * T_);
    const unsigned* wp = (const unsigned*)(P1T + p * T_);
    float s = 0.f;
    for (int t2 = 0; t2 < T_ / 2; ++t2) {
      unsigned ua = ap[t2], uw = wp[t2];
      s = fmaf(bflo(ua), bflo(uw), s);
      s = fmaf(bfhi(ua), bfhi(uw), s);
    }
    hp[nl * 96 + p] = tanhf(s + P1b[p]);
  }
  __syncthreads();

  #pragma unroll
  for (int it = 0; it < 24; ++it) {
    int idx = tid + it * 256;        // < 6144 = 32*192
    int nl = idx / 192, jj = idx % 192;
    const float* hr = hp + nl * 96;
    const unsigned* wp = (const unsigned*)(P2T + jj * 96);
    float s = 0.f;
    for (int p2 = 0; p2 < 48; ++p2) {
      unsigned uw = wp[p2];
      s = fmaf(hr[p2 * 2], bflo(uw), s);
      s = fmaf(hr[p2 * 2 + 1], bfhi(uw), s);
    }
    s += P2b[jj];
    int n = n0 + nl;
    if (n < N_) {
      int pout = jj >> 1;
      size_t o = ((size_t)b * P_ + pout) * N_ + n;
      if ((jj & 1) == 0) {
        dout[o] = s;
      } else {
        float sp = (s > 20.f) ? s : log1pf(expf(s));
        dout[(size_t)B_ * P_ * N_ + 1 + o] = sp + 1e-6f;
      }
    }
  }
  if (b == 0 && blockIdx.x == 0 && tid == 0)
    dout[(size_t)B_ * P_ * N_] = loss_partial[0] + loss_partial[1];
}

// ----------------------------------------------------------------------------------
extern "C" void kernel_launch(void* const* d_in, const int* in_sizes, int n_in,
                              void* d_out, int out_size, void* d_ws, size_t ws_size,
                              hipStream_t stream) {
  const float* x   = (const float*)d_in[0];
  const float* Wg  = (const float*)d_in[11];
  const float* We1 = (const float*)d_in[12];
  const float* be1 = (const float*)d_in[13];
  const float* We2 = (const float*)d_in[14];
  const float* be2 = (const float*)d_in[15];
  const float* P1w = (const float*)d_in[16];
  const float* P1b = (const float*)d_in[17];
  const float* P2w = (const float*)d_in[18];
  const float* P2b = (const float*)d_in[19];

  char* ws = (char*)d_ws;
  size_t off = 0;
  auto alloc = [&](size_t bytes) -> void* {
    void* p = ws + off;
    off += (bytes + 255) & ~(size_t)255;
    return p;
  };
  float* out        = (float*)alloc((size_t)B_ * T_ * N_ * 4);
  bf16*  Abuf       = (bf16*) alloc((size_t)B_ * NPAD * TPAD * 2);
  bf16*  W1T        = (bf16*) alloc((size_t)L_ * E_ * F_ * TPAD * 2);
  bf16*  W2T        = (bf16*) alloc((size_t)L_ * E_ * TTPAD * F_ * 2);
  bf16*  P1T        = (bf16*) alloc((size_t)P_ * T_ * 2);
  bf16*  P2T        = (bf16*) alloc((size_t)2 * P_ * P_ * 2);
  bf16*  h          = (bf16*) alloc((size_t)B_ * 2 * NPAD * F_ * 2);
  float* logits     = (float*)alloc(B_ * E_ * 4);
  int*   pair_e     = (int*)  alloc(B_ * 2 * 4);
  float* pair_gate  = (float*)alloc(B_ * 2 * 4);
  float* loss_part  = (float*)alloc(2 * 4);
  if (ws_size < off) return;  // workspace too small — bail instead of corrupting

  dim3 tb(32, 8);
  // weight prep (transposed, K-contiguous, bf16, zero-padded)
  transpose_cast_kernel<<<dim3(11, 64, 8), tb, 0, stream>>>(
      We1, W1T, T_, F_, TPAD, F_, (long long)T_ * F_, (long long)F_ * TPAD);
  transpose_cast_kernel<<<dim3(64, 12, 8), tb, 0, stream>>>(
      We2, W2T, F_, T_, F_, TTPAD, (long long)F_ * T_, (long long)TTPAD * F_);
  transpose_cast_kernel<<<dim3(11, 3, 1), tb, 0, stream>>>(
      P1w, P1T, T_, P_, T_, P_, 0, 0);
  transpose_cast_kernel<<<dim3(3, 6, 1), tb, 0, stream>>>(
      P2w, P2T, P_, 2 * P_, P_, 2 * P_, 0, 0);

  revin_kernel<<<dim3(B_, 2), 192, 0, stream>>>(x, out);
  pack_kernel<<<dim3(11, 12, B_), tb, 0, stream>>>(out, Abuf, be2, pair_e, pair_gate, -1);

  for (int l = 0; l < L_; ++l) {
    gate1_kernel<<<B_, 384, 0, stream>>>(out, Wg, logits, l);
    gate2_kernel<<<1, 64, 0, stream>>>(logits, pair_e, pair_gate, loss_part, l);
    gemm1_kernel<<<dim3(16, 3, 64), 256, 0, stream>>>(Abuf, W1T, be1, pair_e, pair_gate, h, l);
    gemm2_kernel<<<dim3(3, 6, B_), 256, 0, stream>>>(h, W2T, pair_e, out, l);
    pack_kernel<<<dim3(11, 12, B_), tb, 0, stream>>>(out, Abuf, be2, pair_e, pair_gate, l);
  }

  proj_kernel<<<dim3(11, B_), 256, 0, stream>>>(Abuf, P1T, P1b, P2T, P2b, loss_part,
                                                (float*)d_out);
}

// Round 3
// 747.884 us; speedup vs baseline: 1.0733x; 1.0733x over previous
//
#include <hip/hip_runtime.h>
#include <hip/hip_bf16.h>
#include <cstdint>
#include <math.h>

#define B_ 32
#define T_ 336
#define N_ 321
#define L_ 2
#define E_ 4
#define F_ 2048
#define P_ 96
#define TPAD 352   // T padded to multiple of 32 (K of GEMM1 / proj stage1)
#define NPAD 384   // N padded to multiple of 128 (M tiles)
#define TTPAD 384  // T padded to multiple of 128 (N tiles of GEMM2)

typedef __hip_bfloat16 bf16;
typedef __attribute__((ext_vector_type(8))) __bf16 bf16x8;
typedef __attribute__((ext_vector_type(4))) float f32x4;

__device__ __forceinline__ void async_copy16(const void* g, void* l) {
  __builtin_amdgcn_global_load_lds(
      (__attribute__((address_space(1))) void*)(uintptr_t)g,
      (__attribute__((address_space(3))) void*)(unsigned int)(uintptr_t)l,
      16, 0, 0);
}

// ---------------- transpose + cast fp32 -> bf16 (K-contiguous operand prep) ----------
__global__ void transpose_cast_kernel(const float* __restrict__ src, bf16* __restrict__ dst,
                                      int R, int C, int Rp, int Cp,
                                      long long sStride, long long dStride) {
  __shared__ float tile[32][33];
  const float* s = src + (size_t)blockIdx.z * sStride;
  bf16* d = dst + (size_t)blockIdx.z * dStride;
  int r0 = blockIdx.x * 32, c0 = blockIdx.y * 32;
  int tx = threadIdx.x, ty = threadIdx.y;
  #pragma unroll
  for (int ii = 0; ii < 4; ii++) {
    int rl = ty * 4 + ii;
    int r = r0 + rl, c = c0 + tx;
    tile[rl][tx] = (r < R && c < C) ? s[(size_t)r * C + c] : 0.f;
  }
  __syncthreads();
  #pragma unroll
  for (int ii = 0; ii < 4; ii++) {
    int cl = ty * 4 + ii;
    int cd = c0 + cl, rd = r0 + tx;
    if (cd < Cp && rd < Rp)
      d[(size_t)cd * Rp + rd] = __float2bfloat16(tile[tx][cl]);
  }
}

// ---------------- RevIN over time axis: out[b,t,n] = (x[b,t,n,0]-mu)/sd -------------
__global__ void revin_kernel(const float* __restrict__ x, float* __restrict__ out) {
  int b = blockIdx.x;
  int n = blockIdx.y * 192 + threadIdx.x;
  if (n >= N_) return;
  const float* xp = x + ((size_t)b * T_ * N_ + n) * 3;
  float s1 = 0.f, s2 = 0.f;
  for (int t = 0; t < T_; t++) {
    float v = xp[(size_t)t * N_ * 3];
    s1 += v; s2 += v * v;
  }
  float mu = s1 / T_;
  float var = s2 / T_ - mu * mu;
  float inv = 1.f / sqrtf(var + 1e-5f);
  for (int t = 0; t < T_; t++) {
    float v = (xp[(size_t)t * N_ * 3] - mu) * inv;
    out[((size_t)b * T_ + t) * N_ + n] = v;
  }
}

// ---------------- pack: out (+ optional per-expert be2 bias) -> Abuf bf16 (B,NPAD,TPAD)
__global__ void pack_kernel(float* __restrict__ out, bf16* __restrict__ Abuf,
                            const float* __restrict__ be2,
                            const int* __restrict__ pair_e, const float* __restrict__ pair_gate,
                            int layer) {
  __shared__ float tile[32][33];
  int b = blockIdx.z;
  int t0 = blockIdx.x * 32, n0 = blockIdx.y * 32;
  int tx = threadIdx.x, ty = threadIdx.y;
  bool dob = layer >= 0;
  float g0 = 0.f, g1 = 0.f; int e0 = 0, e1 = 0;
  if (dob) {
    e0 = pair_e[b * 2]; e1 = pair_e[b * 2 + 1];
    g0 = pair_gate[b * 2]; g1 = pair_gate[b * 2 + 1];
  }
  #pragma unroll
  for (int ii = 0; ii < 4; ii++) {
    int i = ty * 4 + ii;
    int t = t0 + i, n = n0 + tx;
    float v = 0.f;
    if (t < T_ && n < N_) {
      v = out[((size_t)b * T_ + t) * N_ + n];
      if (dob) {
        v += g0 * be2[(layer * E_ + e0) * T_ + t] + g1 * be2[(layer * E_ + e1) * T_ + t];
        out[((size_t)b * T_ + t) * N_ + n] = v;
      }
    }
    tile[i][tx] = v;
  }
  __syncthreads();
  #pragma unroll
  for (int ii = 0; ii < 4; ii++) {
    int i = ty * 4 + ii;           // n-local
    int n = n0 + i, t = t0 + tx;
    if (n < NPAD && t < TPAD)
      Abuf[((size_t)b * NPAD + n) * TPAD + t] = __float2bfloat16(tile[tx][i]);
  }
}

// ---------------- gating: logits[b,e] = (mean_n out[b,t,n]) @ Wg[l] -----------------
__global__ void gate1_kernel(const float* __restrict__ out, const float* __restrict__ Wg,
                             float* __restrict__ logits, int layer) {
  __shared__ float red[4][512];
  int b = blockIdx.x, tid = threadIdx.x; // 384 threads
  float cm = 0.f;
  if (tid < T_) {
    const float* p = out + ((size_t)b * T_ + tid) * N_;
    float s = 0.f;
    for (int n = 0; n < N_; n++) s += p[n];
    cm = s / (float)N_;
  }
  #pragma unroll
  for (int e = 0; e < 4; e++)
    red[e][tid] = (tid < T_) ? cm * Wg[(layer * T_ + tid) * E_ + e] : 0.f;
  if (tid < 128) {
    #pragma unroll
    for (int e = 0; e < 4; e++) red[e][384 + tid] = 0.f;
  }
  __syncthreads();
  for (int s = 256; s > 0; s >>= 1) {
    if (tid < s) {
      #pragma unroll
      for (int e = 0; e < 4; e++) red[e][tid] += red[e][tid + s];
    }
    __syncthreads();
  }
  if (tid < 4) logits[b * 4 + tid] = red[tid][0];
}

// top-2 + softmax + importance + cv^2 loss
__global__ void gate2_kernel(const float* __restrict__ logits, int* __restrict__ pair_e,
                             float* __restrict__ pair_gate, float* __restrict__ loss_partial,
                             int layer) {
  __shared__ float gates[32][4];
  __shared__ float imp[4];
  int tid = threadIdx.x;
  if (tid < 32) {
    float v[4];
    #pragma unroll
    for (int e = 0; e < 4; e++) v[e] = logits[tid * 4 + e];
    int i0 = 0;
    for (int e = 1; e < 4; e++) if (v[e] > v[i0]) i0 = e;     // lowest index wins ties
    int i1 = -1;
    for (int e = 0; e < 4; e++) {
      if (e == i0) continue;
      if (i1 < 0 || v[e] > v[i1]) i1 = e;
    }
    float ex = expf(v[i1] - v[i0]);
    float g0 = 1.f / (1.f + ex);
    float g1 = ex / (1.f + ex);
    pair_e[tid * 2] = i0; pair_e[tid * 2 + 1] = i1;
    pair_gate[tid * 2] = g0; pair_gate[tid * 2 + 1] = g1;
    #pragma unroll
    for (int e = 0; e < 4; e++) gates[tid][e] = 0.f;
    gates[tid][i0] = g0; gates[tid][i1] = g1;
  }
  __syncthreads();
  if (tid < 4) {
    float s = 0.f;
    for (int bb = 0; bb < 32; bb++) s += gates[bb][tid];
    imp[tid] = s;
  }
  __syncthreads();
  if (tid == 0) {
    float m = (imp[0] + imp[1] + imp[2] + imp[3]) * 0.25f;
    float va = 0.f;
    #pragma unroll
    for (int e = 0; e < 4; e++) { float d = imp[e] - m; va += d * d; }
    va *= 0.25f;
    loss_partial[layer] = 0.01f * (va / (m * m + 1e-10f));
  }
}

// ---------------- GEMM1: h[pair] = gate * relu(Abuf[b] @ We1[l,e] + be1) ------------
__global__ __launch_bounds__(256) void gemm1_kernel(
    const bf16* __restrict__ Abuf, const bf16* __restrict__ W1T,
    const float* __restrict__ be1, const int* __restrict__ pair_e,
    const float* __restrict__ pair_gate, bf16* __restrict__ h, int layer) {
  __shared__ __align__(16) bf16 As[128 * 32];
  __shared__ __align__(16) bf16 Bs[128 * 32];
  __shared__ float bias_s[128];

  const int tid = threadIdx.x;
  const int w = tid >> 6, lane = tid & 63;
  const int pair = blockIdx.z;
  const int b = pair >> 1;
  const int e = pair_e[pair];
  const float gate = pair_gate[pair];
  const int m0 = blockIdx.y * 128;  // n-dim
  const int f0 = blockIdx.x * 128;

  const bf16* Ag = Abuf + (size_t)b * NPAD * TPAD + (size_t)m0 * TPAD;
  const bf16* Bg = W1T + ((size_t)(layer * E_ + e) * F_ + f0) * TPAD;
  if (tid < 128) bias_s[tid] = be1[(size_t)(layer * E_ + e) * F_ + f0 + tid];

  f32x4 acc[4][4];
  const f32x4 zero = {0.f, 0.f, 0.f, 0.f};
  #pragma unroll
  for (int i = 0; i < 4; i++)
    #pragma unroll
    for (int j = 0; j < 4; j++) acc[i][j] = zero;

  const int wm = w >> 1, wn = w & 1;
  const int lrow = lane >> 2;
  const int lkoff = (lane & 3) * 8;
  const int quad = lane >> 4;
  const int l15 = lane & 15;

  for (int kk = 0; kk < TPAD / 32; ++kk) {
    const int k0 = kk * 32;
    #pragma unroll
    for (int i = 0; i < 2; i++) {
      int r = (w * 2 + i) * 16 + lrow;
      async_copy16(Ag + (size_t)r * TPAD + k0 + lkoff, As + (w * 2 + i) * 512);
    }
    #pragma unroll
    for (int i = 0; i < 2; i++) {
      int r = (w * 2 + i) * 16 + lrow;
      async_copy16(Bg + (size_t)r * TPAD + k0 + lkoff, Bs + (w * 2 + i) * 512);
    }
    __syncthreads();
    bf16x8 af[4], bfr[4];
    #pragma unroll
    for (int mi = 0; mi < 4; mi++)
      af[mi] = *(const bf16x8*)(As + (wm * 64 + mi * 16 + l15) * 32 + quad * 8);
    #pragma unroll
    for (int ni = 0; ni < 4; ni++)
      bfr[ni] = *(const bf16x8*)(Bs + (wn * 64 + ni * 16 + l15) * 32 + quad * 8);
    #pragma unroll
    for (int mi = 0; mi < 4; mi++)
      #pragma unroll
      for (int ni = 0; ni < 4; ni++)
        acc[mi][ni] = __builtin_amdgcn_mfma_f32_16x16x32_bf16(af[mi], bfr[ni], acc[mi][ni], 0, 0, 0);
    __syncthreads();
  }

  // epilogue: bias + relu + gate, LDS transpose for coalesced bf16 stores
  bf16* tw0 = As + w * 1024;
  bf16* tw1 = Bs + w * 1024;
  size_t hbase = (size_t)pair * NPAD * F_ + f0 + wn * 64;
  #pragma unroll
  for (int mi = 0; mi < 4; mi++) {
    bf16* tw = (mi & 1) ? tw1 : tw0;
    #pragma unroll
    for (int ni = 0; ni < 4; ni++) {
      float bias = bias_s[wn * 64 + ni * 16 + l15];
      #pragma unroll
      for (int r = 0; r < 4; r++) {
        float v = acc[mi][ni][r] + bias;
        v = fmaxf(v, 0.f) * gate;
        tw[(quad * 4 + r) * 64 + ni * 16 + l15] = __float2bfloat16(v);
      }
    }
    int row = lane >> 2;            // 0..15
    int fpart = (lane & 3) * 16;    // 0,16,32,48
    int ng = m0 + wm * 64 + mi * 16 + row;
    const uint4* sp = (const uint4*)(tw + row * 64 + fpart);
    uint4 d0 = sp[0];
    uint4 d1 = sp[1];
    uint4* dp = (uint4*)(h + hbase + (size_t)ng * F_ + fpart);
    dp[0] = d0; dp[1] = d1;
  }
}

// ---------------- GEMM2: out[b,t,n] += sum_j h[b*2+j] @ We2[l,e_j]  (K=4096) --------
__global__ __launch_bounds__(256) void gemm2_kernel(
    const bf16* __restrict__ h, const bf16* __restrict__ W2T,
    const int* __restrict__ pair_e, float* __restrict__ out, int layer) {
  __shared__ __align__(16) bf16 As2[64 * 32];
  __shared__ __align__(16) bf16 Bs2[128 * 32];
  const int tid = threadIdx.x;
  const int w = tid >> 6, lane = tid & 63;
  const int b = blockIdx.z;
  const int n0 = blockIdx.y * 64;
  const int t0 = blockIdx.x * 128;
  const int e0 = pair_e[b * 2], e1 = pair_e[b * 2 + 1];
  const bf16* A0 = h + (size_t)(b * 2) * NPAD * F_ + (size_t)n0 * F_;
  const bf16* A1 = h + (size_t)(b * 2 + 1) * NPAD * F_ + (size_t)n0 * F_;
  const bf16* B0 = W2T + ((size_t)(layer * E_ + e0) * TTPAD + t0) * F_;
  const bf16* B1 = W2T + ((size_t)(layer * E_ + e1) * TTPAD + t0) * F_;
  const int lrow = lane >> 2, lkoff = (lane & 3) * 8, quad = lane >> 4, l15 = lane & 15;
  const int wm = w >> 1, wn = w & 1;

  f32x4 acc[2][4];
  const f32x4 zero = {0.f, 0.f, 0.f, 0.f};
  #pragma unroll
  for (int i = 0; i < 2; i++)
    #pragma unroll
    for (int j = 0; j < 4; j++) acc[i][j] = zero;

  for (int kk = 0; kk < 128; ++kk) {
    const bf16* Ab = (kk < 64) ? A0 : A1;
    const bf16* Bb = (kk < 64) ? B0 : B1;
    const int fl = (kk & 63) * 32;
    async_copy16(Ab + (size_t)(w * 16 + lrow) * F_ + fl + lkoff, As2 + w * 512);
    #pragma unroll
    for (int i = 0; i < 2; i++) {
      int r = (w * 2 + i) * 16 + lrow;
      async_copy16(Bb + (size_t)r * F_ + fl + lkoff, Bs2 + (w * 2 + i) * 512);
    }
    __syncthreads();
    bf16x8 af[2], bfr[4];
    #pragma unroll
    for (int mi = 0; mi < 2; mi++)
      af[mi] = *(const bf16x8*)(As2 + (wm * 32 + mi * 16 + l15) * 32 + quad * 8);
    #pragma unroll
    for (int ni = 0; ni < 4; ni++)
      bfr[ni] = *(const bf16x8*)(Bs2 + (wn * 64 + ni * 16 + l15) * 32 + quad * 8);
    #pragma unroll
    for (int mi = 0; mi < 2; mi++)
      #pragma unroll
      for (int ni = 0; ni < 4; ni++)
        acc[mi][ni] = __builtin_amdgcn_mfma_f32_16x16x32_bf16(af[mi], bfr[ni], acc[mi][ni], 0, 0, 0);
    __syncthreads();
  }

  #pragma unroll
  for (int mi = 0; mi < 2; mi++) {
    #pragma unroll
    for (int ni = 0; ni < 4; ni++) {
      int n = n0 + wm * 32 + mi * 16 + quad * 4;
      int t = t0 + wn * 64 + ni * 16 + l15;
      if (t < T_) {
        float* po = out + ((size_t)b * T_ + t) * N_ + n;
        #pragma unroll
        for (int r = 0; r < 4; r++)
          if (n + r < N_) po[r] += acc[mi][ni][r];
      }
    }
  }
}

// ---------------- projection head: fused two-stage MFMA -----------------------------
// Stage1: hp = tanh(Abuf_rows(128) @ P1T^T + P1b)   M=128, N=96, K=TPAD
// Stage2: p  = hp @ P2T^T + P2b                     M=128, N=192 (2 halves), K=96
// grid (NPAD/128, B_), 256 threads (4 waves, each owns 32 M-rows).
#define HS_STRIDE 104  // 96 + 8 pad (208B row stride, 16B-aligned; 2-way aliasing free)
__global__ __launch_bounds__(256) void proj_kernel(
    const bf16* __restrict__ Abuf, const bf16* __restrict__ P1T, const float* __restrict__ P1b,
    const bf16* __restrict__ P2T, const float* __restrict__ P2b,
    const float* __restrict__ loss_partial, float* __restrict__ dout) {
  __shared__ __align__(16) bf16 Hs[128 * HS_STRIDE];
  const int tid = threadIdx.x;
  const int w = tid >> 6, lane = tid & 63;
  const int quad = lane >> 4, l15 = lane & 15;
  const int b = blockIdx.y;
  const int m0 = blockIdx.x * 128;

  // ---- stage 1: direct-global MFMA, M-rows w*32..w*32+31 per wave
  f32x4 acc1[2][6];
  const f32x4 zero = {0.f, 0.f, 0.f, 0.f};
  #pragma unroll
  for (int i = 0; i < 2; i++)
    #pragma unroll
    for (int j = 0; j < 6; j++) acc1[i][j] = zero;

  const bf16* Arow = Abuf + ((size_t)b * NPAD + m0 + w * 32) * TPAD;
  for (int kk = 0; kk < TPAD / 32; ++kk) {
    bf16x8 af[2], bfr[6];
    #pragma unroll
    for (int mi = 0; mi < 2; mi++)
      af[mi] = *(const bf16x8*)(Arow + (size_t)(mi * 16 + l15) * TPAD + kk * 32 + quad * 8);
    #pragma unroll
    for (int ni = 0; ni < 6; ni++)
      bfr[ni] = *(const bf16x8*)(P1T + (size_t)(ni * 16 + l15) * TPAD + kk * 32 + quad * 8);
    #pragma unroll
    for (int mi = 0; mi < 2; mi++)
      #pragma unroll
      for (int ni = 0; ni < 6; ni++)
        acc1[mi][ni] = __builtin_amdgcn_mfma_f32_16x16x32_bf16(af[mi], bfr[ni], acc1[mi][ni], 0, 0, 0);
  }

  // tanh + write to Hs (C-layout -> row-major), each wave touches only its own rows
  #pragma unroll
  for (int mi = 0; mi < 2; mi++) {
    #pragma unroll
    for (int ni = 0; ni < 6; ni++) {
      float bias = P1b[ni * 16 + l15];
      #pragma unroll
      for (int r = 0; r < 4; r++) {
        float x = acc1[mi][ni][r] + bias;
        float t = 1.f - 2.f / (__expf(2.f * x) + 1.f);
        Hs[(w * 32 + mi * 16 + quad * 4 + r) * HS_STRIDE + ni * 16 + l15] = __float2bfloat16(t);
      }
    }
  }
  __syncthreads();

  // ---- stage 2: K=96, A from Hs, B direct from global; two 96-col halves
  #pragma unroll
  for (int half = 0; half < 2; ++half) {
    f32x4 acc2[2][6];
    #pragma unroll
    for (int i = 0; i < 2; i++)
      #pragma unroll
      for (int j = 0; j < 6; j++) acc2[i][j] = zero;

    #pragma unroll
    for (int kk = 0; kk < 3; ++kk) {
      bf16x8 af[2], bfr[6];
      #pragma unroll
      for (int mi = 0; mi < 2; mi++)
        af[mi] = *(const bf16x8*)(Hs + (w * 32 + mi * 16 + l15) * HS_STRIDE + kk * 32 + quad * 8);
      #pragma unroll
      for (int ni = 0; ni < 6; ni++)
        bfr[ni] = *(const bf16x8*)(P2T + (size_t)((half * 6 + ni) * 16 + l15) * P_ + kk * 32 + quad * 8);
      #pragma unroll
      for (int mi = 0; mi < 2; mi++)
        #pragma unroll
        for (int ni = 0; ni < 6; ni++)
          acc2[mi][ni] = __builtin_amdgcn_mfma_f32_16x16x32_bf16(af[mi], bfr[ni], acc2[mi][ni], 0, 0, 0);
    }

    // epilogue: mean / softplus-std scatter
    #pragma unroll
    for (int mi = 0; mi < 2; mi++) {
      #pragma unroll
      for (int ni = 0; ni < 6; ni++) {
        int jj = (half * 6 + ni) * 16 + l15;
        float bias = P2b[jj];
        int pout = jj >> 1;
        #pragma unroll
        for (int r = 0; r < 4; r++) {
          int n = m0 + w * 32 + mi * 16 + quad * 4 + r;
          if (n < N_) {
            float s = acc2[mi][ni][r] + bias;
            size_t o = ((size_t)b * P_ + pout) * N_ + n;
            if ((jj & 1) == 0) {
              dout[o] = s;
            } else {
              float sp = (s > 20.f) ? s : log1pf(__expf(s));
              dout[(size_t)B_ * P_ * N_ + 1 + o] = sp + 1e-6f;
            }
          }
        }
      }
    }
  }
  if (b == 0 && blockIdx.x == 0 && tid == 0)
    dout[(size_t)B_ * P_ * N_] = loss_partial[0] + loss_partial[1];
}

// ----------------------------------------------------------------------------------
extern "C" void kernel_launch(void* const* d_in, const int* in_sizes, int n_in,
                              void* d_out, int out_size, void* d_ws, size_t ws_size,
                              hipStream_t stream) {
  const float* x   = (const float*)d_in[0];
  const float* Wg  = (const float*)d_in[11];
  const float* We1 = (const float*)d_in[12];
  const float* be1 = (const float*)d_in[13];
  const float* We2 = (const float*)d_in[14];
  const float* be2 = (const float*)d_in[15];
  const float* P1w = (const float*)d_in[16];
  const float* P1b = (const float*)d_in[17];
  const float* P2w = (const float*)d_in[18];
  const float* P2b = (const float*)d_in[19];

  char* ws = (char*)d_ws;
  size_t off = 0;
  auto alloc = [&](size_t bytes) -> void* {
    void* p = ws + off;
    off += (bytes + 255) & ~(size_t)255;
    return p;
  };
  float* out        = (float*)alloc((size_t)B_ * T_ * N_ * 4);
  bf16*  Abuf       = (bf16*) alloc((size_t)B_ * NPAD * TPAD * 2);
  bf16*  W1T        = (bf16*) alloc((size_t)L_ * E_ * F_ * TPAD * 2);
  bf16*  W2T        = (bf16*) alloc((size_t)L_ * E_ * TTPAD * F_ * 2);
  bf16*  P1T        = (bf16*) alloc((size_t)P_ * TPAD * 2);
  bf16*  P2T        = (bf16*) alloc((size_t)2 * P_ * P_ * 2);
  bf16*  h          = (bf16*) alloc((size_t)B_ * 2 * NPAD * F_ * 2);
  float* logits     = (float*)alloc(B_ * E_ * 4);
  int*   pair_e     = (int*)  alloc(B_ * 2 * 4);
  float* pair_gate  = (float*)alloc(B_ * 2 * 4);
  float* loss_part  = (float*)alloc(2 * 4);
  if (ws_size < off) return;  // workspace too small — bail instead of corrupting

  dim3 tb(32, 8);
  // weight prep (transposed, K-contiguous, bf16, zero-padded)
  transpose_cast_kernel<<<dim3(11, 64, 8), tb, 0, stream>>>(
      We1, W1T, T_, F_, TPAD, F_, (long long)T_ * F_, (long long)F_ * TPAD);
  transpose_cast_kernel<<<dim3(64, 12, 8), tb, 0, stream>>>(
      We2, W2T, F_, T_, F_, TTPAD, (long long)F_ * T_, (long long)TTPAD * F_);
  transpose_cast_kernel<<<dim3(11, 3, 1), tb, 0, stream>>>(
      P1w, P1T, T_, P_, TPAD, P_, 0, 0);   // padded K to TPAD for uniform stage-1 loop
  transpose_cast_kernel<<<dim3(3, 6, 1), tb, 0, stream>>>(
      P2w, P2T, P_, 2 * P_, P_, 2 * P_, 0, 0);

  revin_kernel<<<dim3(B_, 2), 192, 0, stream>>>(x, out);
  pack_kernel<<<dim3(11, 12, B_), tb, 0, stream>>>(out, Abuf, be2, pair_e, pair_gate, -1);

  for (int l = 0; l < L_; ++l) {
    gate1_kernel<<<B_, 384, 0, stream>>>(out, Wg, logits, l);
    gate2_kernel<<<1, 64, 0, stream>>>(logits, pair_e, pair_gate, loss_part, l);
    gemm1_kernel<<<dim3(16, 3, 64), 256, 0, stream>>>(Abuf, W1T, be1, pair_e, pair_gate, h, l);
    gemm2_kernel<<<dim3(3, 6, B_), 256, 0, stream>>>(h, W2T, pair_e, out, l);
    pack_kernel<<<dim3(11, 12, B_), tb, 0, stream>>>(out, Abuf, be2, pair_e, pair_gate, l);
  }

  proj_kernel<<<dim3(3, B_), 256, 0, stream>>>(Abuf, P1T, P1b, P2T, P2b, loss_part,
                                               (float*)d_out);
}

// Round 4
// 696.403 us; speedup vs baseline: 1.1526x; 1.0739x over previous
//
#include <hip/hip_runtime.h>
#include <hip/hip_bf16.h>
#include <cstdint>
#include <math.h>

#define B_ 32
#define T_ 336
#define N_ 321
#define L_ 2
#define E_ 4
#define F_ 2048
#define P_ 96
#define TPAD 352   // T padded to multiple of 32 (K of GEMM1 / proj stage1)
#define NPAD 384   // N padded to multiple of 128 (M tiles)
#define TTPAD 384  // T padded to multiple of 128 (N tiles of GEMM2)

typedef __hip_bfloat16 bf16;
typedef __attribute__((ext_vector_type(8))) __bf16 bf16x8;
typedef __attribute__((ext_vector_type(4))) float f32x4;

__device__ __forceinline__ void async_copy16(const void* g, void* l) {
  __builtin_amdgcn_global_load_lds(
      (__attribute__((address_space(1))) void*)(uintptr_t)g,
      (__attribute__((address_space(3))) void*)(unsigned int)(uintptr_t)l,
      16, 0, 0);
}

// ---------------- transpose + cast fp32 -> bf16 (K-contiguous operand prep) ----------
__global__ void transpose_cast_kernel(const float* __restrict__ src, bf16* __restrict__ dst,
                                      int R, int C, int Rp, int Cp,
                                      long long sStride, long long dStride) {
  __shared__ float tile[32][33];
  const float* s = src + (size_t)blockIdx.z * sStride;
  bf16* d = dst + (size_t)blockIdx.z * dStride;
  int r0 = blockIdx.x * 32, c0 = blockIdx.y * 32;
  int tx = threadIdx.x, ty = threadIdx.y;
  #pragma unroll
  for (int ii = 0; ii < 4; ii++) {
    int rl = ty * 4 + ii;
    int r = r0 + rl, c = c0 + tx;
    tile[rl][tx] = (r < R && c < C) ? s[(size_t)r * C + c] : 0.f;
  }
  __syncthreads();
  #pragma unroll
  for (int ii = 0; ii < 4; ii++) {
    int cl = ty * 4 + ii;
    int cd = c0 + cl, rd = r0 + tx;
    if (cd < Cp && rd < Rp)
      d[(size_t)cd * Rp + rd] = __float2bfloat16(tile[tx][cl]);
  }
}

// ---------------- RevIN over time axis: out[b,t,n] = (x[b,t,n,0]-mu)/sd -------------
__global__ void revin_kernel(const float* __restrict__ x, float* __restrict__ out) {
  int b = blockIdx.x;
  int n = blockIdx.y * 192 + threadIdx.x;
  if (n >= N_) return;
  const float* xp = x + ((size_t)b * T_ * N_ + n) * 3;
  float s1 = 0.f, s2 = 0.f;
  for (int t = 0; t < T_; t++) {
    float v = xp[(size_t)t * N_ * 3];
    s1 += v; s2 += v * v;
  }
  float mu = s1 / T_;
  float var = s2 / T_ - mu * mu;
  float inv = 1.f / sqrtf(var + 1e-5f);
  for (int t = 0; t < T_; t++) {
    float v = (xp[(size_t)t * N_ * 3] - mu) * inv;
    out[((size_t)b * T_ + t) * N_ + n] = v;
  }
}

// ---------------- pack: out (+= P0+P1 + gated be2) -> out, Abuf bf16 (B,NPAD,TPAD) --
// layer < 0: initial pack (no partial merge, no bias).
#define PSLAB ((size_t)B_ * T_ * N_)
__global__ void pack_kernel(float* __restrict__ out, bf16* __restrict__ Abuf,
                            const float* __restrict__ be2, const float* __restrict__ P,
                            const int* __restrict__ pair_e, const float* __restrict__ pair_gate,
                            int layer) {
  __shared__ float tile[32][33];
  int b = blockIdx.z;
  int t0 = blockIdx.x * 32, n0 = blockIdx.y * 32;
  int tx = threadIdx.x, ty = threadIdx.y;
  bool dob = layer >= 0;
  float g0 = 0.f, g1 = 0.f; int e0 = 0, e1 = 0;
  if (dob) {
    e0 = pair_e[b * 2]; e1 = pair_e[b * 2 + 1];
    g0 = pair_gate[b * 2]; g1 = pair_gate[b * 2 + 1];
  }
  #pragma unroll
  for (int ii = 0; ii < 4; ii++) {
    int i = ty * 4 + ii;
    int t = t0 + i, n = n0 + tx;
    float v = 0.f;
    if (t < T_ && n < N_) {
      size_t q = ((size_t)b * T_ + t) * N_ + n;
      v = out[q];
      if (dob) {
        v += P[q] + P[PSLAB + q];   // split-expert partial merge
        v += g0 * be2[(layer * E_ + e0) * T_ + t] + g1 * be2[(layer * E_ + e1) * T_ + t];
        out[q] = v;
      }
    }
    tile[i][tx] = v;
  }
  __syncthreads();
  #pragma unroll
  for (int ii = 0; ii < 4; ii++) {
    int i = ty * 4 + ii;           // n-local
    int n = n0 + i, t = t0 + tx;
    if (n < NPAD && t < TPAD)
      Abuf[((size_t)b * NPAD + n) * TPAD + t] = __float2bfloat16(tile[tx][i]);
  }
}

// ---------------- gating: logits[b,e] = (mean_n out[b,t,n]) @ Wg[l] -----------------
__global__ void gate1_kernel(const float* __restrict__ out, const float* __restrict__ Wg,
                             float* __restrict__ logits, int layer) {
  __shared__ float red[4][512];
  int b = blockIdx.x, tid = threadIdx.x; // 384 threads
  float cm = 0.f;
  if (tid < T_) {
    const float* p = out + ((size_t)b * T_ + tid) * N_;
    float s = 0.f;
    for (int n = 0; n < N_; n++) s += p[n];
    cm = s / (float)N_;
  }
  #pragma unroll
  for (int e = 0; e < 4; e++)
    red[e][tid] = (tid < T_) ? cm * Wg[(layer * T_ + tid) * E_ + e] : 0.f;
  if (tid < 128) {
    #pragma unroll
    for (int e = 0; e < 4; e++) red[e][384 + tid] = 0.f;
  }
  __syncthreads();
  for (int s = 256; s > 0; s >>= 1) {
    if (tid < s) {
      #pragma unroll
      for (int e = 0; e < 4; e++) red[e][tid] += red[e][tid + s];
    }
    __syncthreads();
  }
  if (tid < 4) logits[b * 4 + tid] = red[tid][0];
}

// top-2 + softmax + importance + cv^2 loss
__global__ void gate2_kernel(const float* __restrict__ logits, int* __restrict__ pair_e,
                             float* __restrict__ pair_gate, float* __restrict__ loss_partial,
                             int layer) {
  __shared__ float gates[32][4];
  __shared__ float imp[4];
  int tid = threadIdx.x;
  if (tid < 32) {
    float v[4];
    #pragma unroll
    for (int e = 0; e < 4; e++) v[e] = logits[tid * 4 + e];
    int i0 = 0;
    for (int e = 1; e < 4; e++) if (v[e] > v[i0]) i0 = e;     // lowest index wins ties
    int i1 = -1;
    for (int e = 0; e < 4; e++) {
      if (e == i0) continue;
      if (i1 < 0 || v[e] > v[i1]) i1 = e;
    }
    float ex = expf(v[i1] - v[i0]);
    float g0 = 1.f / (1.f + ex);
    float g1 = ex / (1.f + ex);
    pair_e[tid * 2] = i0; pair_e[tid * 2 + 1] = i1;
    pair_gate[tid * 2] = g0; pair_gate[tid * 2 + 1] = g1;
    #pragma unroll
    for (int e = 0; e < 4; e++) gates[tid][e] = 0.f;
    gates[tid][i0] = g0; gates[tid][i1] = g1;
  }
  __syncthreads();
  if (tid < 4) {
    float s = 0.f;
    for (int bb = 0; bb < 32; bb++) s += gates[bb][tid];
    imp[tid] = s;
  }
  __syncthreads();
  if (tid == 0) {
    float m = (imp[0] + imp[1] + imp[2] + imp[3]) * 0.25f;
    float va = 0.f;
    #pragma unroll
    for (int e = 0; e < 4; e++) { float d = imp[e] - m; va += d * d; }
    va *= 0.25f;
    loss_partial[layer] = 0.01f * (va / (m * m + 1e-10f));
  }
}

// ---------------- GEMM1: h[pair] = gate * relu(Abuf[b] @ We1[l,e] + be1) ------------
__global__ __launch_bounds__(256) void gemm1_kernel(
    const bf16* __restrict__ Abuf, const bf16* __restrict__ W1T,
    const float* __restrict__ be1, const int* __restrict__ pair_e,
    const float* __restrict__ pair_gate, bf16* __restrict__ h, int layer) {
  __shared__ __align__(16) bf16 As[128 * 32];
  __shared__ __align__(16) bf16 Bs[128 * 32];
  __shared__ float bias_s[128];

  const int tid = threadIdx.x;
  const int w = tid >> 6, lane = tid & 63;
  const int pair = blockIdx.z;
  const int b = pair >> 1;
  const int e = pair_e[pair];
  const float gate = pair_gate[pair];
  const int m0 = blockIdx.y * 128;  // n-dim
  const int f0 = blockIdx.x * 128;

  const bf16* Ag = Abuf + (size_t)b * NPAD * TPAD + (size_t)m0 * TPAD;
  const bf16* Bg = W1T + ((size_t)(layer * E_ + e) * F_ + f0) * TPAD;
  if (tid < 128) bias_s[tid] = be1[(size_t)(layer * E_ + e) * F_ + f0 + tid];

  f32x4 acc[4][4];
  const f32x4 zero = {0.f, 0.f, 0.f, 0.f};
  #pragma unroll
  for (int i = 0; i < 4; i++)
    #pragma unroll
    for (int j = 0; j < 4; j++) acc[i][j] = zero;

  const int wm = w >> 1, wn = w & 1;
  const int lrow = lane >> 2;
  const int lkoff = (lane & 3) * 8;
  const int quad = lane >> 4;
  const int l15 = lane & 15;

  for (int kk = 0; kk < TPAD / 32; ++kk) {
    const int k0 = kk * 32;
    #pragma unroll
    for (int i = 0; i < 2; i++) {
      int r = (w * 2 + i) * 16 + lrow;
      async_copy16(Ag + (size_t)r * TPAD + k0 + lkoff, As + (w * 2 + i) * 512);
    }
    #pragma unroll
    for (int i = 0; i < 2; i++) {
      int r = (w * 2 + i) * 16 + lrow;
      async_copy16(Bg + (size_t)r * TPAD + k0 + lkoff, Bs + (w * 2 + i) * 512);
    }
    __syncthreads();
    bf16x8 af[4], bfr[4];
    #pragma unroll
    for (int mi = 0; mi < 4; mi++)
      af[mi] = *(const bf16x8*)(As + (wm * 64 + mi * 16 + l15) * 32 + quad * 8);
    #pragma unroll
    for (int ni = 0; ni < 4; ni++)
      bfr[ni] = *(const bf16x8*)(Bs + (wn * 64 + ni * 16 + l15) * 32 + quad * 8);
    #pragma unroll
    for (int mi = 0; mi < 4; mi++)
      #pragma unroll
      for (int ni = 0; ni < 4; ni++)
        acc[mi][ni] = __builtin_amdgcn_mfma_f32_16x16x32_bf16(af[mi], bfr[ni], acc[mi][ni], 0, 0, 0);
    __syncthreads();
  }

  // epilogue: bias + relu + gate, LDS transpose for coalesced bf16 stores
  bf16* tw0 = As + w * 1024;
  bf16* tw1 = Bs + w * 1024;
  size_t hbase = (size_t)pair * NPAD * F_ + f0 + wn * 64;
  #pragma unroll
  for (int mi = 0; mi < 4; mi++) {
    bf16* tw = (mi & 1) ? tw1 : tw0;
    #pragma unroll
    for (int ni = 0; ni < 4; ni++) {
      float bias = bias_s[wn * 64 + ni * 16 + l15];
      #pragma unroll
      for (int r = 0; r < 4; r++) {
        float v = acc[mi][ni][r] + bias;
        v = fmaxf(v, 0.f) * gate;
        tw[(quad * 4 + r) * 64 + ni * 16 + l15] = __float2bfloat16(v);
      }
    }
    int row = lane >> 2;            // 0..15
    int fpart = (lane & 3) * 16;    // 0,16,32,48
    int ng = m0 + wm * 64 + mi * 16 + row;
    const uint4* sp = (const uint4*)(tw + row * 64 + fpart);
    uint4 d0 = sp[0];
    uint4 d1 = sp[1];
    uint4* dp = (uint4*)(h + hbase + (size_t)ng * F_ + fpart);
    dp[0] = d0; dp[1] = d1;
  }
}

// ---------------- GEMM2 (split-expert): P[j][b,t,n] = h[b*2+j] @ We2[l,e_j] ---------
// One expert per block (K=2048). Tile 64(n) x 192(t). grid (2, 6, 64).
// Each (j,b,t,n) is written by exactly one block -> plain stores, no RMW races.
__global__ __launch_bounds__(256) void gemm2_kernel(
    const bf16* __restrict__ h, const bf16* __restrict__ W2T,
    const int* __restrict__ pair_e, float* __restrict__ P, int layer) {
  __shared__ __align__(16) bf16 As2[64 * 32];    // 4 chunks of 512
  __shared__ __align__(16) bf16 Bs2[192 * 32];   // 12 chunks of 512
  const int tid = threadIdx.x;
  const int w = tid >> 6, lane = tid & 63;
  const int pair = blockIdx.z;
  const int b = pair >> 1, j = pair & 1;
  const int n0 = blockIdx.y * 64;
  const int t0 = blockIdx.x * 192;
  const int e = pair_e[pair];
  const bf16* Ag = h + (size_t)pair * NPAD * F_ + (size_t)n0 * F_;
  const bf16* Bg = W2T + ((size_t)(layer * E_ + e) * TTPAD + t0) * F_;
  const int lrow = lane >> 2, lkoff = (lane & 3) * 8, quad = lane >> 4, l15 = lane & 15;
  const int wm = w >> 1, wt = w & 1;   // wave tile: 32(n) x 96(t)

  f32x4 acc[2][6];
  const f32x4 zero = {0.f, 0.f, 0.f, 0.f};
  #pragma unroll
  for (int i = 0; i < 2; i++)
    #pragma unroll
    for (int jj = 0; jj < 6; jj++) acc[i][jj] = zero;

  for (int kk = 0; kk < 64; ++kk) {
    const int fl = kk * 32;
    // A: wave w stages rows 16w..16w+15 -> chunk w
    async_copy16(Ag + (size_t)(w * 16 + lrow) * F_ + fl + lkoff, As2 + w * 512);
    // B: wave w stages row-chunks 3w..3w+2
    #pragma unroll
    for (int i = 0; i < 3; i++) {
      int r = w * 48 + i * 16 + lrow;
      async_copy16(Bg + (size_t)r * F_ + fl + lkoff, Bs2 + (w * 3 + i) * 512);
    }
    __syncthreads();
    bf16x8 af[2], bfr[6];
    #pragma unroll
    for (int mi = 0; mi < 2; mi++)
      af[mi] = *(const bf16x8*)(As2 + (wm * 2 + mi) * 512 + l15 * 32 + quad * 8);
    #pragma unroll
    for (int ni = 0; ni < 6; ni++)
      bfr[ni] = *(const bf16x8*)(Bs2 + (wt * 6 + ni) * 512 + l15 * 32 + quad * 8);
    #pragma unroll
    for (int mi = 0; mi < 2; mi++)
      #pragma unroll
      for (int ni = 0; ni < 6; ni++)
        acc[mi][ni] = __builtin_amdgcn_mfma_f32_16x16x32_bf16(af[mi], bfr[ni], acc[mi][ni], 0, 0, 0);
    __syncthreads();
  }

  float* Pj = P + (size_t)j * PSLAB;
  #pragma unroll
  for (int mi = 0; mi < 2; mi++) {
    #pragma unroll
    for (int ni = 0; ni < 6; ni++) {
      int n = n0 + wm * 32 + mi * 16 + quad * 4;
      int t = t0 + wt * 96 + ni * 16 + l15;
      if (t < T_) {
        float* po = Pj + ((size_t)b * T_ + t) * N_ + n;
        #pragma unroll
        for (int r = 0; r < 4; r++)
          if (n + r < N_) po[r] = acc[mi][ni][r];
      }
    }
  }
}

// ---------------- projection head: fused two-stage MFMA -----------------------------
#define HS_STRIDE 104  // 96 + 8 pad (208B row stride, 16B-aligned; 2-way aliasing free)
__global__ __launch_bounds__(256) void proj_kernel(
    const bf16* __restrict__ Abuf, const bf16* __restrict__ P1T, const float* __restrict__ P1b,
    const bf16* __restrict__ P2T, const float* __restrict__ P2b,
    const float* __restrict__ loss_partial, float* __restrict__ dout) {
  __shared__ __align__(16) bf16 Hs[128 * HS_STRIDE];
  const int tid = threadIdx.x;
  const int w = tid >> 6, lane = tid & 63;
  const int quad = lane >> 4, l15 = lane & 15;
  const int b = blockIdx.y;
  const int m0 = blockIdx.x * 128;

  f32x4 acc1[2][6];
  const f32x4 zero = {0.f, 0.f, 0.f, 0.f};
  #pragma unroll
  for (int i = 0; i < 2; i++)
    #pragma unroll
    for (int j = 0; j < 6; j++) acc1[i][j] = zero;

  const bf16* Arow = Abuf + ((size_t)b * NPAD + m0 + w * 32) * TPAD;
  for (int kk = 0; kk < TPAD / 32; ++kk) {
    bf16x8 af[2], bfr[6];
    #pragma unroll
    for (int mi = 0; mi < 2; mi++)
      af[mi] = *(const bf16x8*)(Arow + (size_t)(mi * 16 + l15) * TPAD + kk * 32 + quad * 8);
    #pragma unroll
    for (int ni = 0; ni < 6; ni++)
      bfr[ni] = *(const bf16x8*)(P1T + (size_t)(ni * 16 + l15) * TPAD + kk * 32 + quad * 8);
    #pragma unroll
    for (int mi = 0; mi < 2; mi++)
      #pragma unroll
      for (int ni = 0; ni < 6; ni++)
        acc1[mi][ni] = __builtin_amdgcn_mfma_f32_16x16x32_bf16(af[mi], bfr[ni], acc1[mi][ni], 0, 0, 0);
  }

  #pragma unroll
  for (int mi = 0; mi < 2; mi++) {
    #pragma unroll
    for (int ni = 0; ni < 6; ni++) {
      float bias = P1b[ni * 16 + l15];
      #pragma unroll
      for (int r = 0; r < 4; r++) {
        float x = acc1[mi][ni][r] + bias;
        float t = 1.f - 2.f / (__expf(2.f * x) + 1.f);
        Hs[(w * 32 + mi * 16 + quad * 4 + r) * HS_STRIDE + ni * 16 + l15] = __float2bfloat16(t);
      }
    }
  }
  __syncthreads();

  #pragma unroll
  for (int half = 0; half < 2; ++half) {
    f32x4 acc2[2][6];
    #pragma unroll
    for (int i = 0; i < 2; i++)
      #pragma unroll
      for (int j = 0; j < 6; j++) acc2[i][j] = zero;

    #pragma unroll
    for (int kk = 0; kk < 3; ++kk) {
      bf16x8 af[2], bfr[6];
      #pragma unroll
      for (int mi = 0; mi < 2; mi++)
        af[mi] = *(const bf16x8*)(Hs + (w * 32 + mi * 16 + l15) * HS_STRIDE + kk * 32 + quad * 8);
      #pragma unroll
      for (int ni = 0; ni < 6; ni++)
        bfr[ni] = *(const bf16x8*)(P2T + (size_t)((half * 6 + ni) * 16 + l15) * P_ + kk * 32 + quad * 8);
      #pragma unroll
      for (int mi = 0; mi < 2; mi++)
        #pragma unroll
        for (int ni = 0; ni < 6; ni++)
          acc2[mi][ni] = __builtin_amdgcn_mfma_f32_16x16x32_bf16(af[mi], bfr[ni], acc2[mi][ni], 0, 0, 0);
    }

    #pragma unroll
    for (int mi = 0; mi < 2; mi++) {
      #pragma unroll
      for (int ni = 0; ni < 6; ni++) {
        int jj = (half * 6 + ni) * 16 + l15;
        float bias = P2b[jj];
        int pout = jj >> 1;
        #pragma unroll
        for (int r = 0; r < 4; r++) {
          int n = m0 + w * 32 + mi * 16 + quad * 4 + r;
          if (n < N_) {
            float s = acc2[mi][ni][r] + bias;
            size_t o = ((size_t)b * P_ + pout) * N_ + n;
            if ((jj & 1) == 0) {
              dout[o] = s;
            } else {
              float sp = (s > 20.f) ? s : log1pf(__expf(s));
              dout[(size_t)B_ * P_ * N_ + 1 + o] = sp + 1e-6f;
            }
          }
        }
      }
    }
  }
  if (b == 0 && blockIdx.x == 0 && tid == 0)
    dout[(size_t)B_ * P_ * N_] = loss_partial[0] + loss_partial[1];
}

// ----------------------------------------------------------------------------------
extern "C" void kernel_launch(void* const* d_in, const int* in_sizes, int n_in,
                              void* d_out, int out_size, void* d_ws, size_t ws_size,
                              hipStream_t stream) {
  const float* x   = (const float*)d_in[0];
  const float* Wg  = (const float*)d_in[11];
  const float* We1 = (const float*)d_in[12];
  const float* be1 = (const float*)d_in[13];
  const float* We2 = (const float*)d_in[14];
  const float* be2 = (const float*)d_in[15];
  const float* P1w = (const float*)d_in[16];
  const float* P1b = (const float*)d_in[17];
  const float* P2w = (const float*)d_in[18];
  const float* P2b = (const float*)d_in[19];

  char* ws = (char*)d_ws;
  size_t off = 0;
  auto alloc = [&](size_t bytes) -> void* {
    void* p = ws + off;
    off += (bytes + 255) & ~(size_t)255;
    return p;
  };
  float* out        = (float*)alloc((size_t)B_ * T_ * N_ * 4);
  bf16*  Abuf       = (bf16*) alloc((size_t)B_ * NPAD * TPAD * 2);
  bf16*  W1T        = (bf16*) alloc((size_t)L_ * E_ * F_ * TPAD * 2);
  bf16*  W2T        = (bf16*) alloc((size_t)L_ * E_ * TTPAD * F_ * 2);
  bf16*  P1T        = (bf16*) alloc((size_t)P_ * TPAD * 2);
  bf16*  P2T        = (bf16*) alloc((size_t)2 * P_ * P_ * 2);
  bf16*  h          = (bf16*) alloc((size_t)B_ * 2 * NPAD * F_ * 2);
  float* Ppart      = (float*)alloc((size_t)2 * B_ * T_ * N_ * 4);
  float* logits     = (float*)alloc(B_ * E_ * 4);
  int*   pair_e     = (int*)  alloc(B_ * 2 * 4);
  float* pair_gate  = (float*)alloc(B_ * 2 * 4);
  float* loss_part  = (float*)alloc(2 * 4);
  if (ws_size < off) return;  // workspace too small — bail instead of corrupting

  dim3 tb(32, 8);
  transpose_cast_kernel<<<dim3(11, 64, 8), tb, 0, stream>>>(
      We1, W1T, T_, F_, TPAD, F_, (long long)T_ * F_, (long long)F_ * TPAD);
  transpose_cast_kernel<<<dim3(64, 12, 8), tb, 0, stream>>>(
      We2, W2T, F_, T_, F_, TTPAD, (long long)F_ * T_, (long long)TTPAD * F_);
  transpose_cast_kernel<<<dim3(11, 3, 1), tb, 0, stream>>>(
      P1w, P1T, T_, P_, TPAD, P_, 0, 0);
  transpose_cast_kernel<<<dim3(3, 6, 1), tb, 0, stream>>>(
      P2w, P2T, P_, 2 * P_, P_, 2 * P_, 0, 0);

  revin_kernel<<<dim3(B_, 2), 192, 0, stream>>>(x, out);
  pack_kernel<<<dim3(11, 12, B_), tb, 0, stream>>>(out, Abuf, be2, Ppart, pair_e, pair_gate, -1);

  for (int l = 0; l < L_; ++l) {
    gate1_kernel<<<B_, 384, 0, stream>>>(out, Wg, logits, l);
    gate2_kernel<<<1, 64, 0, stream>>>(logits, pair_e, pair_gate, loss_part, l);
    gemm1_kernel<<<dim3(16, 3, 64), 256, 0, stream>>>(Abuf, W1T, be1, pair_e, pair_gate, h, l);
    gemm2_kernel<<<dim3(2, 6, 64), 256, 0, stream>>>(h, W2T, pair_e, Ppart, l);
    pack_kernel<<<dim3(11, 12, B_), tb, 0, stream>>>(out, Abuf, be2, Ppart, pair_e, pair_gate, l);
  }

  proj_kernel<<<dim3(3, B_), 256, 0, stream>>>(Abuf, P1T, P1b, P2T, P2b, loss_part,
                                               (float*)d_out);
}